// Round 3
// baseline (343.905 us; speedup 1.0000x reference)
//
#include <hip/hip_runtime.h>
#include <hip/hip_fp16.h>
#include <math.h>

#define CAP 64          // max incidences per node (mean deg = 8)
#define D1 128
#define D2 16
#define C_OUT 40
#define K_EDGE 32
#define CLAMP_LO 1e-7f
#define CLAMP_HI 10.0f
#define SQRT_INV31 0.1796053020267749f   // sqrt(1/31)

// Build per-node incidence lists + transpose W1 (first 2048 threads).
__global__ void k_build(const int* __restrict__ idx, int* __restrict__ deg,
                        int* __restrict__ lst, float* __restrict__ W1t,
                        const float* __restrict__ W1, int total) {
    int i = blockIdx.x * blockDim.x + threadIdx.x;
    if (i < D1 * D2) W1t[(i & 15) * D1 + (i >> 4)] = W1[i];  // W1t[c][row]
    if (i >= total) return;
    int n = idx[i];
    int e = i >> 5;                 // k = 32
    int pos = atomicAdd(&deg[n], 1);
    if (pos < CAP) lst[n * CAP + pos] = e;
}

// Hp = clip(x, 1e-7, 10)^2 stored as fp16
__global__ void k_clip_sq(const float* __restrict__ x, __half2* __restrict__ Hp, int total4) {
    int i = blockIdx.x * blockDim.x + threadIdx.x;
    if (i >= total4) return;
    float4 v = ((const float4*)x)[i];
    v.x = fminf(fmaxf(v.x, CLAMP_LO), CLAMP_HI);
    v.y = fminf(fmaxf(v.y, CLAMP_LO), CLAMP_HI);
    v.z = fminf(fmaxf(v.z, CLAMP_LO), CLAMP_HI);
    v.w = fminf(fmaxf(v.w, CLAMP_LO), CLAMP_HI);
    Hp[2 * i]     = __floats2half2_rn(v.x * v.x, v.y * v.y);
    Hp[2 * i + 1] = __floats2half2_rn(v.z * v.z, v.w * v.w);
}

// S[e,:] = sum of Hp[node,:] over the edge's 32 nodes. One wave per edge,
// 4 edges per block. readlane -> scalar base -> saddr loads.
__global__ __launch_bounds__(256) void k_edge_sum(const __half2* __restrict__ Hp,
                                                  const int* __restrict__ idx,
                                                  __half2* __restrict__ S, int E) {
    int w = threadIdx.x >> 6;
    int lane = threadIdx.x & 63;
    int e = blockIdx.x * 4 + w;                 // E % 4 == 0
    int nid = (lane < K_EDGE) ? idx[e * K_EDGE + lane] : 0;
    float a0 = 0.0f, a1 = 0.0f;
#pragma unroll
    for (int j = 0; j < K_EDGE; j++) {
        int n = __builtin_amdgcn_readlane(nid, j);
        __half2 h = Hp[(size_t)n * 64 + lane];
        a0 += __low2float(h);
        a1 += __high2float(h);
    }
    S[(size_t)e * 64 + lane] = __floats2half2_rn(a0, a1);
}

// Fused layer-1 node kernel. One wave per node (lane = 2 cols), 4 nodes/block.
__global__ __launch_bounds__(256) void k_node1(const __half2* __restrict__ Hp,
                                               const __half2* __restrict__ S,
                                               const int* __restrict__ deg,
                                               const int* __restrict__ lst,
                                               const float* __restrict__ W1t,
                                               const float* __restrict__ b1,
                                               float* __restrict__ Hp2, int N) {
    int w = threadIdx.x >> 6;
    int lane = threadIdx.x & 63;
    int n = blockIdx.x * 4 + w;                 // N % 4 == 0
    int c = lane & 15, j = lane >> 4;

    // W1 fragment: 8 float4 in staggered order so the matmul pairs literal
    // register index with the staggered (conflict-free) LDS read.
    float4 wq[8];
    const float4* w1p = (const float4*)(W1t + c * D1 + j * 32);
#pragma unroll
    for (int t = 0; t < 8; t++) wq[t] = w1p[(2 * j + t) & 7];

    __half2 hph = Hp[(size_t)n * 64 + lane];
    int dgc = min(deg[n], CAP);
    int e_r = (lane < dgc) ? lst[n * CAP + lane] : 0;
    float hp0 = __low2float(hph), hp1 = __high2float(hph);

    float acc0 = 0.0f, acc1 = 0.0f;
    int t = 0;
    for (; t + 4 <= dgc; t += 4) {
        int e0 = __builtin_amdgcn_readlane(e_r, t);
        int e1 = __builtin_amdgcn_readlane(e_r, t + 1);
        int e2 = __builtin_amdgcn_readlane(e_r, t + 2);
        int e3 = __builtin_amdgcn_readlane(e_r, t + 3);
        __half2 s0 = S[(size_t)e0 * 64 + lane];
        __half2 s1 = S[(size_t)e1 * 64 + lane];
        __half2 s2 = S[(size_t)e2 * 64 + lane];
        __half2 s3 = S[(size_t)e3 * 64 + lane];
        acc0 += __builtin_amdgcn_sqrtf(fmaxf(__low2float(s0)  - hp0, 0.0f));
        acc1 += __builtin_amdgcn_sqrtf(fmaxf(__high2float(s0) - hp1, 0.0f));
        acc0 += __builtin_amdgcn_sqrtf(fmaxf(__low2float(s1)  - hp0, 0.0f));
        acc1 += __builtin_amdgcn_sqrtf(fmaxf(__high2float(s1) - hp1, 0.0f));
        acc0 += __builtin_amdgcn_sqrtf(fmaxf(__low2float(s2)  - hp0, 0.0f));
        acc1 += __builtin_amdgcn_sqrtf(fmaxf(__high2float(s2) - hp1, 0.0f));
        acc0 += __builtin_amdgcn_sqrtf(fmaxf(__low2float(s3)  - hp0, 0.0f));
        acc1 += __builtin_amdgcn_sqrtf(fmaxf(__high2float(s3) - hp1, 0.0f));
    }
    for (; t < dgc; t++) {
        int e = __builtin_amdgcn_readlane(e_r, t);
        __half2 sh = S[(size_t)e * 64 + lane];
        acc0 += __builtin_amdgcn_sqrtf(fmaxf(__low2float(sh)  - hp0, 0.0f));
        acc1 += __builtin_amdgcn_sqrtf(fmaxf(__high2float(sh) - hp1, 0.0f));
    }
    float ns0 = __builtin_amdgcn_sqrtf(hp0) + acc0 * SQRT_INV31;
    float ns1 = __builtin_amdgcn_sqrtf(hp1) + acc1 * SQRT_INV31;

    __shared__ float AHs[4][D1];
    AHs[w][2 * lane]     = ns0;      // unnormalized; fold r into epilogue
    AHs[w][2 * lane + 1] = ns1;

    // rowsum butterfly (overlaps with LDS drain)
    float v = ns0 + ns1;
#pragma unroll
    for (int m = 1; m < 64; m <<= 1) v += __shfl_xor(v, m, 64);
    float r = __builtin_amdgcn_rcpf(v);

    __syncthreads();

    // ns[128] @ W1[128,16]: lane (c,j), group j covers rows j*32..j*32+31
    // via 8 staggered ds_read_b128 (banks 8j+4t+k: conflict-free).
    const float4* ahp = (const float4*)(&AHs[w][j * 32]);
    float p = 0.0f;
#pragma unroll
    for (int tt = 0; tt < 8; tt++) {
        float4 ah = ahp[(2 * j + tt) & 7];
        float4 wv = wq[tt];
        p += ah.x * wv.x + ah.y * wv.y + ah.z * wv.z + ah.w * wv.w;
    }
    p += __shfl_xor(p, 16, 64);
    p += __shfl_xor(p, 32, 64);
    if (lane < D2) {
        float o = b1[c] + p * r;
        float cl = fminf(fmaxf(o, CLAMP_LO), CLAMP_HI);   // relu + next clip
        Hp2[(size_t)n * D2 + c] = cl * cl;
    }
}

// S2[e,:] = sum over 32 nodes of Hp2[node,:] (d=16, fp32).
__global__ __launch_bounds__(256) void k_edge_sum2(const float* __restrict__ Hp2,
                                                   const int* __restrict__ idx,
                                                   float* __restrict__ S2, int E) {
    int e = blockIdx.x * 16 + (threadIdx.x >> 4);
    int col = threadIdx.x & 15;
    if (e >= E) return;
    float acc = 0.0f;
#pragma unroll
    for (int j = 0; j < K_EDGE; j++) {
        int n = idx[e * K_EDGE + j];
        acc += Hp2[(size_t)n * D2 + col];
    }
    S2[(size_t)e * D2 + col] = acc;
}

// Fused layer-2 node kernel: aggregate + normalize + @W2 + b2 -> out[N,40].
__global__ __launch_bounds__(256) void k_node2(const float* __restrict__ Hp2,
                                               const float* __restrict__ S2,
                                               const int* __restrict__ deg,
                                               const int* __restrict__ lst,
                                               const float* __restrict__ W2,
                                               const float* __restrict__ b2,
                                               float* __restrict__ out, int N) {
    int w = threadIdx.x >> 6;
    int lane = threadIdx.x & 63;
    int n = blockIdx.x * 4 + w;                 // N % 4 == 0

    int col = lane & 15;
    int g = lane >> 4;
    float hp = Hp2[(size_t)n * D2 + col];
    int dgc = min(deg[n], CAP);
    int e_r = (lane < dgc) ? lst[n * CAP + lane] : 0;

    float acc = 0.0f;
    for (int t = g; t < dgc; t += 4) {
        int e = __shfl(e_r, t, 64);
        acc += __builtin_amdgcn_sqrtf(fmaxf(S2[(size_t)e * D2 + col] - hp, 0.0f));
    }
    acc += __shfl_xor(acc, 16, 64);
    acc += __shfl_xor(acc, 32, 64);
    float ns = __builtin_amdgcn_sqrtf(hp) + acc * SQRT_INV31;

    float v = ns;
#pragma unroll
    for (int m = 1; m < 16; m <<= 1) v += __shfl_xor(v, m, 64);
    float r = __builtin_amdgcn_rcpf(v);

    __shared__ float AHs[4][D2];
    if (lane < D2) AHs[w][lane] = ns * r;
    __syncthreads();

    if (lane < C_OUT) {
        float o = b2[lane];
#pragma unroll
        for (int i = 0; i < D2; i++)
            o += AHs[w][i] * W2[i * C_OUT + lane];
        out[(size_t)n * C_OUT + lane] = o;
    }
}

extern "C" void kernel_launch(void* const* d_in, const int* in_sizes, int n_in,
                              void* d_out, int out_size, void* d_ws, size_t ws_size,
                              hipStream_t stream) {
    const float* x   = (const float*)d_in[0];
    const int*   idx = (const int*)d_in[1];
    const float* W1  = (const float*)d_in[2];
    const float* b1  = (const float*)d_in[3];
    const float* W2  = (const float*)d_in[4];
    const float* b2  = (const float*)d_in[5];
    float* out = (float*)d_out;

    int N = in_sizes[0] / D1;     // 100000
    int E = in_sizes[1] / K_EDGE; // 25000

    // workspace layout
    __half2* Hp = (__half2*)d_ws;                          // N*64 half2
    __half2* S  = Hp + (size_t)N * 64;                     // E*64 half2
    float* Hp2  = (float*)(S + (size_t)E * 64);            // N*16 fp32
    float* S2   = Hp2 + (size_t)N * D2;                    // E*16 fp32
    float* W1t  = S2 + (size_t)E * D2;                     // 16*128 fp32 (transposed W1)
    int*   deg  = (int*)(W1t + D1 * D2);                   // N
    int*   lst  = deg + N;                                 // N*CAP

    int total = E * K_EDGE;

    hipMemsetAsync(deg, 0, (size_t)N * sizeof(int), stream);
    k_clip_sq<<<((N * D1 / 4) + 255) / 256, 256, 0, stream>>>(x, Hp, N * D1 / 4);
    k_build<<<(total + 255) / 256, 256, 0, stream>>>(idx, deg, lst, W1t, W1, total);
    k_edge_sum<<<E / 4, 256, 0, stream>>>(Hp, idx, S, E);
    k_node1<<<N / 4, 256, 0, stream>>>(Hp, S, deg, lst, W1t, b1, Hp2, N);
    k_edge_sum2<<<(E + 15) / 16, 256, 0, stream>>>(Hp2, idx, S2, E);
    k_node2<<<N / 4, 256, 0, stream>>>(Hp2, S2, deg, lst, W2, b2, out, N);
}

// Round 5
// 342.200 us; speedup vs baseline: 1.0050x; 1.0050x over previous
//
#include <hip/hip_runtime.h>
#include <hip/hip_fp16.h>
#include <math.h>

#define CAP 64          // max incidences per node (mean deg = 8)
#define D1 128
#define D2 16
#define C_OUT 40
#define K_EDGE 32
#define CLAMP_LO 1e-7f
#define CLAMP_HI 10.0f
#define SQRT_INV31 0.1796053020267749f   // sqrt(1/31)

// Build per-node incidence lists + transpose W1 (first 2048 threads).
__global__ void k_build(const int* __restrict__ idx, int* __restrict__ deg,
                        int* __restrict__ lst, float* __restrict__ W1t,
                        const float* __restrict__ W1, int total) {
    int i = blockIdx.x * blockDim.x + threadIdx.x;
    if (i < D1 * D2) W1t[(i & 15) * D1 + (i >> 4)] = W1[i];  // W1t[c][row]
    if (i >= total) return;
    int n = idx[i];
    int e = i >> 5;                 // k = 32
    int pos = atomicAdd(&deg[n], 1);
    if (pos < CAP) lst[n * CAP + pos] = e;
}

// Hp = clip(x, 1e-7, 10)^2 stored as fp16
__global__ void k_clip_sq(const float* __restrict__ x, __half2* __restrict__ Hp, int total4) {
    int i = blockIdx.x * blockDim.x + threadIdx.x;
    if (i >= total4) return;
    float4 v = ((const float4*)x)[i];
    v.x = fminf(fmaxf(v.x, CLAMP_LO), CLAMP_HI);
    v.y = fminf(fmaxf(v.y, CLAMP_LO), CLAMP_HI);
    v.z = fminf(fmaxf(v.z, CLAMP_LO), CLAMP_HI);
    v.w = fminf(fmaxf(v.w, CLAMP_LO), CLAMP_HI);
    Hp[2 * i]     = __floats2half2_rn(v.x * v.x, v.y * v.y);
    Hp[2 * i + 1] = __floats2half2_rn(v.z * v.z, v.w * v.w);
}

// S[e,:] = sum of Hp[node,:] over the edge's 32 nodes. One wave per edge,
// 4 edges per block. readlane -> scalar base -> saddr loads, 32 independent.
__global__ __launch_bounds__(256) void k_edge_sum(const __half2* __restrict__ Hp,
                                                  const int* __restrict__ idx,
                                                  __half2* __restrict__ S, int E) {
    int w = threadIdx.x >> 6;
    int lane = threadIdx.x & 63;
    int e = blockIdx.x * 4 + w;                 // E % 4 == 0
    int nid = (lane < K_EDGE) ? idx[e * K_EDGE + lane] : 0;
    float a0 = 0.0f, a1 = 0.0f;
#pragma unroll
    for (int j = 0; j < K_EDGE; j++) {
        int n = __builtin_amdgcn_readlane(nid, j);
        __half2 h = Hp[(size_t)n * 64 + lane];
        a0 += __low2float(h);
        a1 += __high2float(h);
    }
    S[(size_t)e * 64 + lane] = __floats2half2_rn(a0, a1);
}

// Fused layer-1 node kernel. One wave per node (lane = 2 cols), 4 nodes/block.
// Fixed unroll-16 gather with zero-row padding (row E of S is all zeros):
// lanes >= deg carry edge id E, whose term sqrt(max(0-hp,0)) == 0.
__global__ __launch_bounds__(256) void k_node1(const __half2* __restrict__ Hp,
                                               const __half2* __restrict__ S,
                                               const int* __restrict__ deg,
                                               const int* __restrict__ lst,
                                               const float* __restrict__ W1t,
                                               const float* __restrict__ b1,
                                               float* __restrict__ Hp2, int N, int E) {
    int w = threadIdx.x >> 6;
    int lane = threadIdx.x & 63;
    int n = blockIdx.x * 4 + w;                 // N % 4 == 0
    int c = lane & 15, j = lane >> 4;

    __half2 hph = Hp[(size_t)n * 64 + lane];
    int dgc = min(deg[n], CAP);
    int e_r = (lane < dgc) ? lst[n * CAP + lane] : E;   // E = zero row

    // 16 independent gathers issued before any use (single vmcnt drain)
    __half2 sv[16];
#pragma unroll
    for (int t = 0; t < 16; t++) {
        int e = __builtin_amdgcn_readlane(e_r, t);
        sv[t] = S[(size_t)e * 64 + lane];
    }

    float hp0 = __low2float(hph), hp1 = __high2float(hph);
    float acc0 = 0.0f, acc1 = 0.0f;
#pragma unroll
    for (int t = 0; t < 16; t++) {
        float s0 = __low2float(sv[t]), s1 = __high2float(sv[t]);
        acc0 += __builtin_amdgcn_sqrtf(fmaxf(s0 - hp0, 0.0f));
        acc1 += __builtin_amdgcn_sqrtf(fmaxf(s1 - hp1, 0.0f));
    }
    for (int t = 16; t < dgc; t++) {            // rare (P ~ 0.4%)
        int e = __builtin_amdgcn_readlane(e_r, t);
        __half2 sh = S[(size_t)e * 64 + lane];
        acc0 += __builtin_amdgcn_sqrtf(fmaxf(__low2float(sh)  - hp0, 0.0f));
        acc1 += __builtin_amdgcn_sqrtf(fmaxf(__high2float(sh) - hp1, 0.0f));
    }
    float ns0 = __builtin_amdgcn_sqrtf(hp0) + acc0 * SQRT_INV31;
    float ns1 = __builtin_amdgcn_sqrtf(hp1) + acc1 * SQRT_INV31;

    __shared__ float AHs[4][D1];
    AHs[w][2 * lane]     = ns0;      // unnormalized; r folded into epilogue
    AHs[w][2 * lane + 1] = ns1;

    float v = ns0 + ns1;
#pragma unroll
    for (int m = 1; m < 64; m <<= 1) v += __shfl_xor(v, m, 64);
    float r = __builtin_amdgcn_rcpf(v);

    __syncthreads();

    // ns[128] @ W1[128,16]: lane (c,j); group j covers rows j*32..j*32+31.
    const float4* ahp = (const float4*)(&AHs[w][j * 32]);
    const float4* w1p = (const float4*)(W1t + c * D1 + j * 32);
    float p = 0.0f;
#pragma unroll
    for (int tt = 0; tt < 8; tt++) {
        float4 ah = ahp[tt];
        float4 wv = w1p[tt];
        p += ah.x * wv.x + ah.y * wv.y + ah.z * wv.z + ah.w * wv.w;
    }
    p += __shfl_xor(p, 16, 64);
    p += __shfl_xor(p, 32, 64);
    if (lane < D2) {
        float o = b1[c] + p * r;
        float cl = fminf(fmaxf(o, CLAMP_LO), CLAMP_HI);   // relu + next clip
        Hp2[(size_t)n * D2 + c] = cl * cl;
    }
}

// S2[e,:] = sum over 32 nodes of Hp2[node,:] (d=16, fp32).
__global__ __launch_bounds__(256) void k_edge_sum2(const float* __restrict__ Hp2,
                                                   const int* __restrict__ idx,
                                                   float* __restrict__ S2, int E) {
    int e = blockIdx.x * 16 + (threadIdx.x >> 4);
    int col = threadIdx.x & 15;
    if (e >= E) return;
    float acc = 0.0f;
#pragma unroll
    for (int j = 0; j < K_EDGE; j++) {
        int n = idx[e * K_EDGE + j];
        acc += Hp2[(size_t)n * D2 + col];
    }
    S2[(size_t)e * D2 + col] = acc;
}

// Fused layer-2 node kernel. One wave per node; lane = col(16) x group(4);
// group g handles edge slots {g, 4+g, 8+g, 12+g} (zero-row padded), rare tail.
__global__ __launch_bounds__(256) void k_node2(const float* __restrict__ Hp2,
                                               const float* __restrict__ S2,
                                               const int* __restrict__ deg,
                                               const int* __restrict__ lst,
                                               const float* __restrict__ W2,
                                               const float* __restrict__ b2,
                                               float* __restrict__ out, int N, int E) {
    int w = threadIdx.x >> 6;
    int lane = threadIdx.x & 63;
    int n = blockIdx.x * 4 + w;                 // N % 4 == 0
    int col = lane & 15;
    int g = lane >> 4;

    float hp = Hp2[(size_t)n * D2 + col];
    int dgc = min(deg[n], CAP);
    int e_r = (lane < dgc) ? lst[n * CAP + lane] : E;   // E = zero row of S2

    int ev[4];
#pragma unroll
    for (int t = 0; t < 4; t++) ev[t] = __shfl(e_r, 4 * t + g, 64);
    float sv[4];
#pragma unroll
    for (int t = 0; t < 4; t++) sv[t] = S2[(size_t)ev[t] * D2 + col];

    float acc = 0.0f;
#pragma unroll
    for (int t = 0; t < 4; t++)
        acc += __builtin_amdgcn_sqrtf(fmaxf(sv[t] - hp, 0.0f));
    for (int tg = 16 + g; tg < dgc; tg += 4) {   // rare
        int e = __shfl(e_r, tg, 64);
        acc += __builtin_amdgcn_sqrtf(fmaxf(S2[(size_t)e * D2 + col] - hp, 0.0f));
    }
    acc += __shfl_xor(acc, 16, 64);
    acc += __shfl_xor(acc, 32, 64);             // all groups: full sum per col
    float ns = __builtin_amdgcn_sqrtf(hp) + acc * SQRT_INV31;

    float v = ns;
#pragma unroll
    for (int m = 1; m < 16; m <<= 1) v += __shfl_xor(v, m, 64);  // rowsum (16 cols)
    float r = __builtin_amdgcn_rcpf(v);

    __shared__ float AHs[4][D2];
    if (lane < D2) AHs[w][lane] = ns * r;
    __syncthreads();

    if (lane < C_OUT) {
        float o = b2[lane];
#pragma unroll
        for (int i = 0; i < D2; i++)
            o += AHs[w][i] * W2[i * C_OUT + lane];
        out[(size_t)n * C_OUT + lane] = o;
    }
}

extern "C" void kernel_launch(void* const* d_in, const int* in_sizes, int n_in,
                              void* d_out, int out_size, void* d_ws, size_t ws_size,
                              hipStream_t stream) {
    const float* x   = (const float*)d_in[0];
    const int*   idx = (const int*)d_in[1];
    const float* W1  = (const float*)d_in[2];
    const float* b1  = (const float*)d_in[3];
    const float* W2  = (const float*)d_in[4];
    const float* b2  = (const float*)d_in[5];
    float* out = (float*)d_out;

    int N = in_sizes[0] / D1;     // 100000
    int E = in_sizes[1] / K_EDGE; // 25000

    // workspace layout (S and S2 have one extra zero row at index E)
    __half2* Hp = (__half2*)d_ws;                          // N*64 half2
    __half2* S  = Hp + (size_t)N * 64;                     // (E+1)*64 half2
    float* Hp2  = (float*)(S + (size_t)(E + 1) * 64);      // N*16 fp32
    float* S2   = Hp2 + (size_t)N * D2;                    // (E+1)*16 fp32
    float* W1t  = S2 + (size_t)(E + 1) * D2;               // 16*128 fp32
    int*   deg  = (int*)(W1t + D1 * D2);                   // N
    int*   lst  = deg + N;                                 // N*CAP

    int total = E * K_EDGE;

    (void)hipMemsetAsync(deg, 0, (size_t)N * sizeof(int), stream);
    (void)hipMemsetAsync(S + (size_t)E * 64, 0, 64 * sizeof(__half2), stream);   // zero row
    (void)hipMemsetAsync(S2 + (size_t)E * D2, 0, D2 * sizeof(float), stream);    // zero row
    k_clip_sq<<<((N * D1 / 4) + 255) / 256, 256, 0, stream>>>(x, Hp, N * D1 / 4);
    k_build<<<(total + 255) / 256, 256, 0, stream>>>(idx, deg, lst, W1t, W1, total);
    k_edge_sum<<<E / 4, 256, 0, stream>>>(Hp, idx, S, E);
    k_node1<<<N / 4, 256, 0, stream>>>(Hp, S, deg, lst, W1t, b1, Hp2, N, E);
    k_edge_sum2<<<(E + 15) / 16, 256, 0, stream>>>(Hp2, idx, S2, E);
    k_node2<<<N / 4, 256, 0, stream>>>(Hp2, S2, deg, lst, W2, b2, out, N, E);
}

// Round 6
// 280.919 us; speedup vs baseline: 1.2242x; 1.2181x over previous
//
#include <hip/hip_runtime.h>
#include <hip/hip_fp16.h>
#include <math.h>

#define CAP 64          // max incidences per node (mean deg = 8)
#define D1 128
#define D2 16
#define C_OUT 40
#define K_EDGE 32
#define CLAMP_LO 1e-7f
#define CLAMP_HI 10.0f
#define SQRT_INV31 0.1796053020267749f   // sqrt(1/31)

// Build per-node incidence lists + transpose W1 (first 2048 threads).
__global__ void k_build(const int* __restrict__ idx, int* __restrict__ deg,
                        int* __restrict__ lst, float* __restrict__ W1t,
                        const float* __restrict__ W1, int total) {
    int i = blockIdx.x * blockDim.x + threadIdx.x;
    if (i < D1 * D2) W1t[(i & 15) * D1 + (i >> 4)] = W1[i];  // W1t[c][row]
    if (i >= total) return;
    int n = idx[i];
    int e = i >> 5;                 // k = 32
    int pos = atomicAdd(&deg[n], 1);
    if (pos < CAP) lst[n * CAP + pos] = e;
}

// Hp = clip(x, 1e-7, 10)^2 stored as fp16
__global__ void k_clip_sq(const float* __restrict__ x, __half2* __restrict__ Hp, int total4) {
    int i = blockIdx.x * blockDim.x + threadIdx.x;
    if (i >= total4) return;
    float4 v = ((const float4*)x)[i];
    v.x = fminf(fmaxf(v.x, CLAMP_LO), CLAMP_HI);
    v.y = fminf(fmaxf(v.y, CLAMP_LO), CLAMP_HI);
    v.z = fminf(fmaxf(v.z, CLAMP_LO), CLAMP_HI);
    v.w = fminf(fmaxf(v.w, CLAMP_LO), CLAMP_HI);
    Hp[2 * i]     = __floats2half2_rn(v.x * v.x, v.y * v.y);
    Hp[2 * i + 1] = __floats2half2_rn(v.z * v.z, v.w * v.w);
}

// S[e,:] = sum of Hp[node,:] over the edge's 32 nodes. One wave per edge,
// 4 edges per block. 32 independent readlane->saddr gathers.
__global__ __launch_bounds__(256) void k_edge_sum(const __half2* __restrict__ Hp,
                                                  const int* __restrict__ idx,
                                                  __half2* __restrict__ S, int E) {
    int w = threadIdx.x >> 6;
    int lane = threadIdx.x & 63;
    int e = blockIdx.x * 4 + w;                 // E % 4 == 0
    int nid = idx[e * K_EDGE + (lane & 31)];    // unconditional, halves duplicated
    float a0 = 0.0f, a1 = 0.0f;
#pragma unroll
    for (int j = 0; j < K_EDGE; j++) {
        int n = __builtin_amdgcn_readlane(nid, j);
        __half2 h = Hp[(size_t)n * 64 + lane];
        a0 += __low2float(h);
        a1 += __high2float(h);
    }
    S[(size_t)e * 64 + lane] = __floats2half2_rn(a0, a1);
}

// Fused layer-1 node kernel. TWO nodes per wave (amortizes deg/lst chain,
// butterflies, epilogue weight loads); 256-thread block = 4 waves = 8 nodes.
// Zero-row padding: lanes >= deg carry edge id E (row E of S is zeros) so
// their term sqrt(max(0-hp,0)) == 0. No __syncthreads: LDS is wave-private.
__global__ __launch_bounds__(256) void k_node1(const __half2* __restrict__ Hp,
                                               const __half2* __restrict__ S,
                                               const int* __restrict__ deg,
                                               const int* __restrict__ lst,
                                               const float* __restrict__ W1t,
                                               const float* __restrict__ b1,
                                               float* __restrict__ Hp2, int N, int E) {
    int w = threadIdx.x >> 6;
    int lane = threadIdx.x & 63;
    int pair = blockIdx.x * 4 + w;              // wave handles nodes 2p, 2p+1
    int n0 = pair * 2, n1 = n0 + 1;             // N even
    int c = lane & 15, j = lane >> 4;

    // deg for both nodes (one 8B uniform load) + unconditional lst loads
    int2 dg2 = ((const int2*)deg)[pair];
    int l0 = lst[n0 * CAP + lane];
    int l1 = lst[n1 * CAP + lane];
    __half2 hph0 = Hp[(size_t)n0 * 64 + lane];
    __half2 hph1 = Hp[(size_t)n1 * 64 + lane];
    int dg0 = min(dg2.x, CAP), dg1 = min(dg2.y, CAP);
    int e0_r = (lane < dg0) ? l0 : E;
    int e1_r = (lane < dg1) ? l1 : E;

    // two bursts of 16 independent gathers (32 in flight per wave)
    __half2 sv0[16], sv1[16];
#pragma unroll
    for (int t = 0; t < 16; t++) {
        int e = __builtin_amdgcn_readlane(e0_r, t);
        sv0[t] = S[(size_t)e * 64 + lane];
    }
#pragma unroll
    for (int t = 0; t < 16; t++) {
        int e = __builtin_amdgcn_readlane(e1_r, t);
        sv1[t] = S[(size_t)e * 64 + lane];
    }

    float hp00 = __low2float(hph0), hp01 = __high2float(hph0);
    float hp10 = __low2float(hph1), hp11 = __high2float(hph1);

    float a00 = 0.0f, a01 = 0.0f, a10 = 0.0f, a11 = 0.0f;
#pragma unroll
    for (int t = 0; t < 16; t++) {
        a00 += __builtin_amdgcn_sqrtf(fmaxf(__low2float(sv0[t])  - hp00, 0.0f));
        a01 += __builtin_amdgcn_sqrtf(fmaxf(__high2float(sv0[t]) - hp01, 0.0f));
    }
#pragma unroll
    for (int t = 0; t < 16; t++) {
        a10 += __builtin_amdgcn_sqrtf(fmaxf(__low2float(sv1[t])  - hp10, 0.0f));
        a11 += __builtin_amdgcn_sqrtf(fmaxf(__high2float(sv1[t]) - hp11, 0.0f));
    }
    for (int t = 16; t < dg0; t++) {            // rare tails (P ~ 0.4%)
        int e = __builtin_amdgcn_readlane(e0_r, t);
        __half2 sh = S[(size_t)e * 64 + lane];
        a00 += __builtin_amdgcn_sqrtf(fmaxf(__low2float(sh)  - hp00, 0.0f));
        a01 += __builtin_amdgcn_sqrtf(fmaxf(__high2float(sh) - hp01, 0.0f));
    }
    for (int t = 16; t < dg1; t++) {
        int e = __builtin_amdgcn_readlane(e1_r, t);
        __half2 sh = S[(size_t)e * 64 + lane];
        a10 += __builtin_amdgcn_sqrtf(fmaxf(__low2float(sh)  - hp10, 0.0f));
        a11 += __builtin_amdgcn_sqrtf(fmaxf(__high2float(sh) - hp11, 0.0f));
    }

    float ns00 = __builtin_amdgcn_sqrtf(hp00) + a00 * SQRT_INV31;
    float ns01 = __builtin_amdgcn_sqrtf(hp01) + a01 * SQRT_INV31;
    float ns10 = __builtin_amdgcn_sqrtf(hp10) + a10 * SQRT_INV31;
    float ns11 = __builtin_amdgcn_sqrtf(hp11) + a11 * SQRT_INV31;

    __shared__ float AHs[4][2][D1];             // wave-private
    AHs[w][0][2 * lane]     = ns00;
    AHs[w][0][2 * lane + 1] = ns01;
    AHs[w][1][2 * lane]     = ns10;
    AHs[w][1][2 * lane + 1] = ns11;

    // rowsum butterflies (unnormalized; fold reciprocal into epilogue)
    float v0 = ns00 + ns01, v1 = ns10 + ns11;
#pragma unroll
    for (int m = 1; m < 64; m <<= 1) {
        v0 += __shfl_xor(v0, m, 64);
        v1 += __shfl_xor(v1, m, 64);
    }
    float r0 = __builtin_amdgcn_rcpf(v0);
    float r1 = __builtin_amdgcn_rcpf(v1);

    __threadfence_block();                      // LDS visibility within wave

    // ns[128] @ W1[128,16] for both nodes, sharing the W1t fragment.
    // lane (c,j): group j covers rows j*32..j*32+31.
    const float4* a0p = (const float4*)(&AHs[w][0][j * 32]);
    const float4* a1p = (const float4*)(&AHs[w][1][j * 32]);
    const float4* w1p = (const float4*)(W1t + c * D1 + j * 32);
    float p0 = 0.0f, p1 = 0.0f;
#pragma unroll
    for (int tt = 0; tt < 8; tt++) {
        float4 wv = w1p[tt];
        float4 x0 = a0p[tt];
        float4 x1 = a1p[tt];
        p0 += x0.x * wv.x + x0.y * wv.y + x0.z * wv.z + x0.w * wv.w;
        p1 += x1.x * wv.x + x1.y * wv.y + x1.z * wv.z + x1.w * wv.w;
    }
    p0 += __shfl_xor(p0, 16, 64);
    p0 += __shfl_xor(p0, 32, 64);
    p1 += __shfl_xor(p1, 16, 64);
    p1 += __shfl_xor(p1, 32, 64);
    if (lane < D2) {
        float bb = b1[c];
        float o0 = bb + p0 * r0;
        float o1 = bb + p1 * r1;
        float cl0 = fminf(fmaxf(o0, CLAMP_LO), CLAMP_HI);   // relu + next clip
        float cl1 = fminf(fmaxf(o1, CLAMP_LO), CLAMP_HI);
        Hp2[(size_t)n0 * D2 + c] = cl0 * cl0;
        Hp2[(size_t)n1 * D2 + c] = cl1 * cl1;
    }
}

// S2[e,:] = sum over 32 nodes of Hp2[node,:] (d=16, fp32).
__global__ __launch_bounds__(256) void k_edge_sum2(const float* __restrict__ Hp2,
                                                   const int* __restrict__ idx,
                                                   float* __restrict__ S2, int E) {
    int e = blockIdx.x * 16 + (threadIdx.x >> 4);
    int col = threadIdx.x & 15;
    if (e >= E) return;
    float acc = 0.0f;
#pragma unroll
    for (int j = 0; j < K_EDGE; j++) {
        int n = idx[e * K_EDGE + j];
        acc += Hp2[(size_t)n * D2 + col];
    }
    S2[(size_t)e * D2 + col] = acc;
}

// Fused layer-2 node kernel. One wave per node; lane = col(16) x group(4);
// group g handles edge slots {g, 4+g, 8+g, 12+g} (zero-row padded), rare tail.
// No __syncthreads: LDS wave-private.
__global__ __launch_bounds__(256) void k_node2(const float* __restrict__ Hp2,
                                               const float* __restrict__ S2,
                                               const int* __restrict__ deg,
                                               const int* __restrict__ lst,
                                               const float* __restrict__ W2,
                                               const float* __restrict__ b2,
                                               float* __restrict__ out, int N, int E) {
    int w = threadIdx.x >> 6;
    int lane = threadIdx.x & 63;
    int n = blockIdx.x * 4 + w;                 // N % 4 == 0
    int col = lane & 15;
    int g = lane >> 4;

    int dgc = deg[n];
    int lv = lst[n * CAP + lane];               // unconditional
    float hp = Hp2[(size_t)n * D2 + col];
    dgc = min(dgc, CAP);
    int e_r = (lane < dgc) ? lv : E;            // E = zero row of S2

    int ev[4];
#pragma unroll
    for (int t = 0; t < 4; t++) ev[t] = __shfl(e_r, 4 * t + g, 64);
    float sv[4];
#pragma unroll
    for (int t = 0; t < 4; t++) sv[t] = S2[(size_t)ev[t] * D2 + col];

    float acc = 0.0f;
#pragma unroll
    for (int t = 0; t < 4; t++)
        acc += __builtin_amdgcn_sqrtf(fmaxf(sv[t] - hp, 0.0f));
    for (int tg = 16 + g; tg < dgc; tg += 4) {   // rare
        int e = __shfl(e_r, tg, 64);
        acc += __builtin_amdgcn_sqrtf(fmaxf(S2[(size_t)e * D2 + col] - hp, 0.0f));
    }
    acc += __shfl_xor(acc, 16, 64);
    acc += __shfl_xor(acc, 32, 64);             // all groups: full sum per col
    float ns = __builtin_amdgcn_sqrtf(hp) + acc * SQRT_INV31;

    float v = ns;
#pragma unroll
    for (int m = 1; m < 16; m <<= 1) v += __shfl_xor(v, m, 64);  // rowsum (16 cols)
    float r = __builtin_amdgcn_rcpf(v);

    __shared__ float AHs[4][D2];                // wave-private
    if (lane < D2) AHs[w][lane] = ns * r;
    __threadfence_block();

    if (lane < C_OUT) {
        float o = b2[lane];
#pragma unroll
        for (int i = 0; i < D2; i++)
            o += AHs[w][i] * W2[i * C_OUT + lane];
        out[(size_t)n * C_OUT + lane] = o;
    }
}

extern "C" void kernel_launch(void* const* d_in, const int* in_sizes, int n_in,
                              void* d_out, int out_size, void* d_ws, size_t ws_size,
                              hipStream_t stream) {
    const float* x   = (const float*)d_in[0];
    const int*   idx = (const int*)d_in[1];
    const float* W1  = (const float*)d_in[2];
    const float* b1  = (const float*)d_in[3];
    const float* W2  = (const float*)d_in[4];
    const float* b2  = (const float*)d_in[5];
    float* out = (float*)d_out;

    int N = in_sizes[0] / D1;     // 100000
    int E = in_sizes[1] / K_EDGE; // 25000

    // workspace layout (S and S2 have one extra zero row at index E)
    __half2* Hp = (__half2*)d_ws;                          // N*64 half2
    __half2* S  = Hp + (size_t)N * 64;                     // (E+1)*64 half2
    float* Hp2  = (float*)(S + (size_t)(E + 1) * 64);      // N*16 fp32
    float* S2   = Hp2 + (size_t)N * D2;                    // (E+1)*16 fp32
    float* W1t  = S2 + (size_t)(E + 1) * D2;               // 16*128 fp32
    int*   deg  = (int*)(W1t + D1 * D2);                   // N
    int*   lst  = deg + N;                                 // N*CAP

    int total = E * K_EDGE;

    (void)hipMemsetAsync(deg, 0, (size_t)N * sizeof(int), stream);
    (void)hipMemsetAsync(S + (size_t)E * 64, 0, 64 * sizeof(__half2), stream);   // zero row
    (void)hipMemsetAsync(S2 + (size_t)E * D2, 0, D2 * sizeof(float), stream);    // zero row
    k_clip_sq<<<((N * D1 / 4) + 255) / 256, 256, 0, stream>>>(x, Hp, N * D1 / 4);
    k_build<<<(total + 255) / 256, 256, 0, stream>>>(idx, deg, lst, W1t, W1, total);
    k_edge_sum<<<E / 4, 256, 0, stream>>>(Hp, idx, S, E);
    k_node1<<<N / 8, 256, 0, stream>>>(Hp, S, deg, lst, W1t, b1, Hp2, N, E);
    k_edge_sum2<<<(E + 15) / 16, 256, 0, stream>>>(Hp2, idx, S2, E);
    k_node2<<<N / 4, 256, 0, stream>>>(Hp2, S2, deg, lst, W2, b2, out, N, E);
}

// Round 7
// 255.401 us; speedup vs baseline: 1.3465x; 1.0999x over previous
//
#include <hip/hip_runtime.h>
#include <hip/hip_fp16.h>
#include <math.h>

#define CAP 64          // max incidences per node (mean deg = 8)
#define D1 128
#define D2 16
#define C_OUT 40
#define K_EDGE 32
#define CLAMP_LO 1e-7f
#define CLAMP_HI 10.0f
#define SQRT_INV31 0.1796053020267749f   // sqrt(1/31)

typedef unsigned short ushort_t;

// Fused setup: clip+square -> Hp (fp16), incidence-list build (uint16 edge
// ids), W1 transpose, and zero rows of S/S2.
__global__ __launch_bounds__(256) void k_setup(const float* __restrict__ x,
                                               __half2* __restrict__ Hp,
                                               const int* __restrict__ idx,
                                               int* __restrict__ deg,
                                               ushort_t* __restrict__ lst,
                                               const float* __restrict__ W1,
                                               float* __restrict__ W1t,
                                               __half2* __restrict__ S,
                                               float* __restrict__ S2,
                                               int n4, int total, int E) {
    int i = blockIdx.x * 256 + threadIdx.x;
    if (i < n4) {                                  // clip + square, 4 floats
        float4 v = ((const float4*)x)[i];
        v.x = fminf(fmaxf(v.x, CLAMP_LO), CLAMP_HI);
        v.y = fminf(fmaxf(v.y, CLAMP_LO), CLAMP_HI);
        v.z = fminf(fmaxf(v.z, CLAMP_LO), CLAMP_HI);
        v.w = fminf(fmaxf(v.w, CLAMP_LO), CLAMP_HI);
        Hp[2 * i]     = __floats2half2_rn(v.x * v.x, v.y * v.y);
        Hp[2 * i + 1] = __floats2half2_rn(v.z * v.z, v.w * v.w);
    }
    if (i < total) {                               // incidence build
        int n = idx[i];
        int e = i >> 5;                            // k = 32
        int pos = atomicAdd(&deg[n], 1);
        if (pos < CAP) lst[n * CAP + pos] = (ushort_t)e;
    }
    if (i < D1 * D2) W1t[(i & 15) * D1 + (i >> 4)] = W1[i];
    if (i < 64) S[(size_t)E * 64 + i] = __floats2half2_rn(0.0f, 0.0f);
    if (i < D2) S2[(size_t)E * D2 + i] = 0.0f;
}

// S[e,:] = sum of Hp[node,:] over the edge's 32 nodes. TWO edges per wave:
// one coalesced 64-id load covers edges eA and eA+1; 64 saddr gathers in
// flight; idx-load/store fixed costs amortized. 8 edges per 256-block.
__global__ __launch_bounds__(256) void k_edge_sum(const __half2* __restrict__ Hp,
                                                  const int* __restrict__ idx,
                                                  __half2* __restrict__ S, int E) {
    int w = threadIdx.x >> 6;
    int lane = threadIdx.x & 63;
    int eA = blockIdx.x * 8 + w * 2;            // E % 8 == 0
    int nid = idx[eA * K_EDGE + lane];          // 32 ids of eA + 32 ids of eA+1
    float a0 = 0.0f, a1 = 0.0f, b0 = 0.0f, b1 = 0.0f;
#pragma unroll
    for (int j = 0; j < K_EDGE; j++) {
        int nA = __builtin_amdgcn_readlane(nid, j);
        int nB = __builtin_amdgcn_readlane(nid, 32 + j);
        __half2 hA = Hp[(size_t)nA * 64 + lane];
        __half2 hB = Hp[(size_t)nB * 64 + lane];
        a0 += __low2float(hA); a1 += __high2float(hA);
        b0 += __low2float(hB); b1 += __high2float(hB);
    }
    S[(size_t)eA * 64 + lane]       = __floats2half2_rn(a0, a1);
    S[(size_t)(eA + 1) * 64 + lane] = __floats2half2_rn(b0, b1);
}

// Fused layer-1 node kernel. TWO nodes per wave; uint16 lst with only slots
// 0..15 loaded (lanes 0-15: node0, 16-31: node1). Zero-row padding: unused
// slots carry edge id E (row E of S is zeros) so sqrt(max(0-hp,0)) == 0.
__global__ __launch_bounds__(256) void k_node1(const __half2* __restrict__ Hp,
                                               const __half2* __restrict__ S,
                                               const int* __restrict__ deg,
                                               const ushort_t* __restrict__ lst,
                                               const float* __restrict__ W1t,
                                               const float* __restrict__ b1,
                                               float* __restrict__ Hp2, int N, int E) {
    int w = threadIdx.x >> 6;
    int lane = threadIdx.x & 63;
    int pair = blockIdx.x * 4 + w;              // wave handles nodes 2p, 2p+1
    int n0 = pair * 2, n1 = n0 + 1;             // N even
    int c = lane & 15, j = lane >> 4;

    int2 dg2 = ((const int2*)deg)[pair];
    int dg0 = min(dg2.x, CAP), dg1 = min(dg2.y, CAP);
    int sl = lane & 15;
    int nodesel = (lane < 16) ? n0 : n1;
    ushort_t idu = (lane < 32) ? lst[nodesel * CAP + sl] : (ushort_t)0;
    int dsel = (lane < 16) ? dg0 : dg1;
    int e_sel = (lane < 32 && sl < dsel) ? (int)idu : E;

    __half2 hph0 = Hp[(size_t)n0 * 64 + lane];
    __half2 hph1 = Hp[(size_t)n1 * 64 + lane];

    // two bursts of 16 independent gathers (32 in flight per wave)
    __half2 sv0[16], sv1[16];
#pragma unroll
    for (int t = 0; t < 16; t++) {
        int e = __builtin_amdgcn_readlane(e_sel, t);
        sv0[t] = S[(size_t)e * 64 + lane];
    }
#pragma unroll
    for (int t = 0; t < 16; t++) {
        int e = __builtin_amdgcn_readlane(e_sel, 16 + t);
        sv1[t] = S[(size_t)e * 64 + lane];
    }

    float hp00 = __low2float(hph0), hp01 = __high2float(hph0);
    float hp10 = __low2float(hph1), hp11 = __high2float(hph1);

    float a00 = 0.0f, a01 = 0.0f, a10 = 0.0f, a11 = 0.0f;
#pragma unroll
    for (int t = 0; t < 16; t++) {
        a00 += __builtin_amdgcn_sqrtf(fmaxf(__low2float(sv0[t])  - hp00, 0.0f));
        a01 += __builtin_amdgcn_sqrtf(fmaxf(__high2float(sv0[t]) - hp01, 0.0f));
    }
#pragma unroll
    for (int t = 0; t < 16; t++) {
        a10 += __builtin_amdgcn_sqrtf(fmaxf(__low2float(sv1[t])  - hp10, 0.0f));
        a11 += __builtin_amdgcn_sqrtf(fmaxf(__high2float(sv1[t]) - hp11, 0.0f));
    }
    for (int t = 16; t < dg0; t++) {            // rare tails (P ~ 0.4%)
        int e = lst[n0 * CAP + t];
        __half2 sh = S[(size_t)e * 64 + lane];
        a00 += __builtin_amdgcn_sqrtf(fmaxf(__low2float(sh)  - hp00, 0.0f));
        a01 += __builtin_amdgcn_sqrtf(fmaxf(__high2float(sh) - hp01, 0.0f));
    }
    for (int t = 16; t < dg1; t++) {
        int e = lst[n1 * CAP + t];
        __half2 sh = S[(size_t)e * 64 + lane];
        a10 += __builtin_amdgcn_sqrtf(fmaxf(__low2float(sh)  - hp10, 0.0f));
        a11 += __builtin_amdgcn_sqrtf(fmaxf(__high2float(sh) - hp11, 0.0f));
    }

    float ns00 = __builtin_amdgcn_sqrtf(hp00) + a00 * SQRT_INV31;
    float ns01 = __builtin_amdgcn_sqrtf(hp01) + a01 * SQRT_INV31;
    float ns10 = __builtin_amdgcn_sqrtf(hp10) + a10 * SQRT_INV31;
    float ns11 = __builtin_amdgcn_sqrtf(hp11) + a11 * SQRT_INV31;

    __shared__ float AHs[4][2][D1];             // wave-private
    AHs[w][0][2 * lane]     = ns00;
    AHs[w][0][2 * lane + 1] = ns01;
    AHs[w][1][2 * lane]     = ns10;
    AHs[w][1][2 * lane + 1] = ns11;

    float v0 = ns00 + ns01, v1 = ns10 + ns11;
#pragma unroll
    for (int m = 1; m < 64; m <<= 1) {
        v0 += __shfl_xor(v0, m, 64);
        v1 += __shfl_xor(v1, m, 64);
    }
    float r0 = __builtin_amdgcn_rcpf(v0);
    float r1 = __builtin_amdgcn_rcpf(v1);

    __threadfence_block();                      // LDS visibility within wave

    // ns[128] @ W1[128,16] for both nodes, sharing the W1t fragment.
    const float4* a0p = (const float4*)(&AHs[w][0][j * 32]);
    const float4* a1p = (const float4*)(&AHs[w][1][j * 32]);
    const float4* w1p = (const float4*)(W1t + c * D1 + j * 32);
    float p0 = 0.0f, p1 = 0.0f;
#pragma unroll
    for (int tt = 0; tt < 8; tt++) {
        float4 wv = w1p[tt];
        float4 x0 = a0p[tt];
        float4 x1 = a1p[tt];
        p0 += x0.x * wv.x + x0.y * wv.y + x0.z * wv.z + x0.w * wv.w;
        p1 += x1.x * wv.x + x1.y * wv.y + x1.z * wv.z + x1.w * wv.w;
    }
    p0 += __shfl_xor(p0, 16, 64);
    p0 += __shfl_xor(p0, 32, 64);
    p1 += __shfl_xor(p1, 16, 64);
    p1 += __shfl_xor(p1, 32, 64);
    if (lane < D2) {
        float bb = b1[c];
        float o0 = bb + p0 * r0;
        float o1 = bb + p1 * r1;
        float cl0 = fminf(fmaxf(o0, CLAMP_LO), CLAMP_HI);   // relu + next clip
        float cl1 = fminf(fmaxf(o1, CLAMP_LO), CLAMP_HI);
        Hp2[(size_t)n0 * D2 + c] = cl0 * cl0;
        Hp2[(size_t)n1 * D2 + c] = cl1 * cl1;
    }
}

// S2[e,:] = sum over 32 nodes of Hp2[node,:] (d=16, fp32).
__global__ __launch_bounds__(256) void k_edge_sum2(const float* __restrict__ Hp2,
                                                   const int* __restrict__ idx,
                                                   float* __restrict__ S2, int E) {
    int e = blockIdx.x * 16 + (threadIdx.x >> 4);
    int col = threadIdx.x & 15;
    if (e >= E) return;
    float acc = 0.0f;
#pragma unroll
    for (int j = 0; j < K_EDGE; j++) {
        int n = idx[e * K_EDGE + j];
        acc += Hp2[(size_t)n * D2 + col];
    }
    S2[(size_t)e * D2 + col] = acc;
}

// Fused layer-2 node kernel. TWO nodes per wave: node = lane bit 5, two
// 16-lane subgroups per node split the 16 gather slots. uint16 lst.
__global__ __launch_bounds__(256) void k_node2(const float* __restrict__ Hp2,
                                               const float* __restrict__ S2,
                                               const int* __restrict__ deg,
                                               const ushort_t* __restrict__ lst,
                                               const float* __restrict__ W2,
                                               const float* __restrict__ b2,
                                               float* __restrict__ out, int N, int E) {
    int w = threadIdx.x >> 6;
    int lane = threadIdx.x & 63;
    int pair = blockIdx.x * 4 + w;
    int n0 = pair * 2, n1 = n0 + 1;
    int col = lane & 15;
    int node = lane >> 5;                       // 0 or 1
    int gg = (lane >> 4) & 1;                   // subgroup within node
    int nn = node ? n1 : n0;

    int2 dg2 = ((const int2*)deg)[pair];
    int dg0 = min(dg2.x, CAP), dg1 = min(dg2.y, CAP);
    int sl = lane & 15;
    ushort_t idu = (lane < 32) ? lst[((lane < 16) ? n0 : n1) * CAP + sl] : (ushort_t)0;
    int dsel = (lane < 16) ? dg0 : dg1;
    int e_sel = (lane < 32 && sl < dsel) ? (int)idu : E;   // E = zero row of S2

    float hp = Hp2[(size_t)nn * D2 + col];
    int dgn = node ? dg1 : dg0;

    // 8 slots per lane: {2t+gg}, t=0..7, from this node's 16 slots
    int ev[8];
#pragma unroll
    for (int t = 0; t < 8; t++) ev[t] = __shfl(e_sel, node * 16 + 2 * t + gg, 64);
    float sv[8];
#pragma unroll
    for (int t = 0; t < 8; t++) sv[t] = S2[(size_t)ev[t] * D2 + col];

    float acc = 0.0f;
#pragma unroll
    for (int t = 0; t < 8; t++)
        acc += __builtin_amdgcn_sqrtf(fmaxf(sv[t] - hp, 0.0f));
    for (int t = 16; t < dgn; t++) {            // rare tail; add once (gg==0)
        int e = lst[nn * CAP + t];
        float s = S2[(size_t)e * D2 + col];
        if (gg == 0) acc += __builtin_amdgcn_sqrtf(fmaxf(s - hp, 0.0f));
    }
    acc += __shfl_xor(acc, 16, 64);             // combine the node's 2 subgroups
    float ns = __builtin_amdgcn_sqrtf(hp) + acc * SQRT_INV31;

    float v = ns;
#pragma unroll
    for (int m = 1; m < 16; m <<= 1) v += __shfl_xor(v, m, 64);  // rowsum (16 cols)
    float r = __builtin_amdgcn_rcpf(v);

    __shared__ float AHs[4][2][D2];             // wave-private
    if (gg == 0) AHs[w][node][col] = ns * r;
    __threadfence_block();

    if (lane < C_OUT) {
        float o0 = b2[lane], o1 = o0;
#pragma unroll
        for (int i = 0; i < D2; i++) {
            float wv = W2[i * C_OUT + lane];
            o0 += AHs[w][0][i] * wv;
            o1 += AHs[w][1][i] * wv;
        }
        out[(size_t)n0 * C_OUT + lane] = o0;
        out[(size_t)n1 * C_OUT + lane] = o1;
    }
}

extern "C" void kernel_launch(void* const* d_in, const int* in_sizes, int n_in,
                              void* d_out, int out_size, void* d_ws, size_t ws_size,
                              hipStream_t stream) {
    const float* x   = (const float*)d_in[0];
    const int*   idx = (const int*)d_in[1];
    const float* W1  = (const float*)d_in[2];
    const float* b1  = (const float*)d_in[3];
    const float* W2  = (const float*)d_in[4];
    const float* b2  = (const float*)d_in[5];
    float* out = (float*)d_out;

    int N = in_sizes[0] / D1;     // 100000
    int E = in_sizes[1] / K_EDGE; // 25000

    // workspace layout (S and S2 have one extra zero row at index E)
    __half2* Hp = (__half2*)d_ws;                          // N*64 half2
    __half2* S  = Hp + (size_t)N * 64;                     // (E+1)*64 half2
    float* Hp2  = (float*)(S + (size_t)(E + 1) * 64);      // N*16 fp32
    float* S2   = Hp2 + (size_t)N * D2;                    // (E+1)*16 fp32
    float* W1t  = S2 + (size_t)(E + 1) * D2;               // 16*128 fp32
    int*   deg  = (int*)(W1t + D1 * D2);                   // N ints
    ushort_t* lst = (ushort_t*)(deg + N);                  // N*CAP uint16

    int total = E * K_EDGE;        // 800000
    int n4 = N * D1 / 4;           // 3200000

    (void)hipMemsetAsync(deg, 0, (size_t)N * sizeof(int), stream);
    k_setup<<<(n4 + 255) / 256, 256, 0, stream>>>(x, Hp, idx, deg, lst, W1, W1t,
                                                  S, S2, n4, total, E);
    k_edge_sum<<<E / 8, 256, 0, stream>>>(Hp, idx, S, E);
    k_node1<<<N / 8, 256, 0, stream>>>(Hp, S, deg, lst, W1t, b1, Hp2, N, E);
    k_edge_sum2<<<(E + 15) / 16, 256, 0, stream>>>(Hp2, idx, S2, E);
    k_node2<<<N / 8, 256, 0, stream>>>(Hp2, S2, deg, lst, W2, b2, out, N, E);
}